// Round 2
// baseline (368.510 us; speedup 1.0000x reference)
//
#include <hip/hip_runtime.h>

#define BSZ 8
#define LSEQ 8192
#define DDIM 256
#define CHUNK 32
#define WARM 48
#define STEPS (CHUNK + WARM)   // 80
#define NCH (LSEQ / CHUNK)     // 256

typedef float f32x4 __attribute__((ext_vector_type(4)));
typedef _Float16 h8 __attribute__((ext_vector_type(8)));

// ---------------- matrix conversions ----------------
// AhT = A^T in fp16 (so scan B-fragments are contiguous); Bh, Ch straight fp16.
__global__ void k_cvt_mats(const float* __restrict__ A, const float* __restrict__ B,
                           const float* __restrict__ C, _Float16* __restrict__ AhT,
                           _Float16* __restrict__ Bh, _Float16* __restrict__ Ch) {
  int r = blockIdx.x, c = threadIdx.x;
  AhT[c * 256 + r] = (_Float16)A[r * 256 + c];
  Bh[r * 256 + c] = (_Float16)B[r * 256 + c];
  Ch[r * 256 + c] = (_Float16)C[r * 256 + c];
}

// ---------------- U = x @ B^T  (x fp32 read directly, converted in-register) ----
// block = 256 thr (4 waves); block covers 64 rows; wave w -> rows [r0+16w, +16), all 256 cols.
// B rows are L2-resident (128 KB fp16, shared by all 1024 blocks).
__global__ __launch_bounds__(256, 2) void k_gemm_u(const float* __restrict__ x,
                                                   const _Float16* __restrict__ Bh,
                                                   _Float16* __restrict__ U) {
  const int tid = threadIdx.x, wv = tid >> 6, lane = tid & 63;
  const int l15 = lane & 15, q = lane >> 4;
  const size_t r0 = (size_t)blockIdx.x * 64 + wv * 16;
  f32x4 acc[16] = {};
#pragma unroll
  for (int kb = 0; kb < 8; ++kb) {
    const float* xp = x + (r0 + l15) * 256 + kb * 32 + q * 8;
    float4 x0 = *(const float4*)xp;
    float4 x1 = *(const float4*)(xp + 4);
    h8 af;
    af[0] = (_Float16)x0.x; af[1] = (_Float16)x0.y; af[2] = (_Float16)x0.z; af[3] = (_Float16)x0.w;
    af[4] = (_Float16)x1.x; af[5] = (_Float16)x1.y; af[6] = (_Float16)x1.z; af[7] = (_Float16)x1.w;
#pragma unroll
    for (int ct = 0; ct < 16; ++ct) {
      h8 bf = *(const h8*)(Bh + (size_t)(ct * 16 + l15) * 256 + kb * 32 + q * 8);
      acc[ct] = __builtin_amdgcn_mfma_f32_16x16x32_f16(af, bf, acc[ct], 0, 0, 0);
    }
  }
#pragma unroll
  for (int ct = 0; ct < 16; ++ct)
#pragma unroll
    for (int r = 0; r < 4; ++r)
      U[(r0 + q * 4 + r) * 256 + ct * 16 + l15] = (_Float16)acc[ct][r];
}

// ---------------- out = S @ C^T  (S fp16, out fp32) ----------------
__global__ __launch_bounds__(256, 2) void k_gemm_out(const _Float16* __restrict__ S,
                                                     const _Float16* __restrict__ Ch,
                                                     float* __restrict__ O) {
  const int tid = threadIdx.x, wv = tid >> 6, lane = tid & 63;
  const int l15 = lane & 15, q = lane >> 4;
  const size_t r0 = (size_t)blockIdx.x * 64 + wv * 16;
  f32x4 acc[16] = {};
#pragma unroll
  for (int kb = 0; kb < 8; ++kb) {
    h8 af = *(const h8*)(S + (r0 + l15) * 256 + kb * 32 + q * 8);
#pragma unroll
    for (int ct = 0; ct < 16; ++ct) {
      h8 bf = *(const h8*)(Ch + (size_t)(ct * 16 + l15) * 256 + kb * 32 + q * 8);
      acc[ct] = __builtin_amdgcn_mfma_f32_16x16x32_f16(af, bf, acc[ct], 0, 0, 0);
    }
  }
#pragma unroll
  for (int ct = 0; ct < 16; ++ct)
#pragma unroll
    for (int r = 0; r < 4; ++r)
      O[(r0 + q * 4 + r) * 256 + ct * 16 + l15] = acc[ct][r];
}

// ---------------- MFMA scan ----------------
// 2048 chains (8 batches x 256 chunks of 32 steps), 16 chains/block -> 128 blocks.
// block bk: batch b = bk>>4, chunks [c0, c0+16) with c0 = (bk&15)*16; chain m -> chunk c0+m.
// Per step: S_new[16x256] = S_old[16x256] @ A + U_t, via f16 MFMA; A^T fragments resident
// in 128 VGPRs/lane; state double-buffered in LDS (row pad 264 halves); U folded into the
// MFMA C-operand; warm-up 48 steps from zero state (||A^48|| <= 0.84^48 ~ 2e-4).
__global__ __launch_bounds__(256, 1) void k_scan(const _Float16* __restrict__ U,
                                                 const _Float16* __restrict__ AhT,
                                                 _Float16* __restrict__ Sh) {
  __shared__ _Float16 S[2][16][264];
  const int tid = threadIdx.x;
  const int wv = tid >> 6, lane = tid & 63;
  const int l15 = lane & 15, q = lane >> 4;
  const int cw = wv * 64;
  const int bk = blockIdx.x;
  const int b = bk >> 4;
  const int c0 = (bk & 15) * 16;

  // A^T fragments: bf[ct][kb] covers output cols [cw+ct*16, +16), k in [kb*32, +32)
  h8 bf[4][8];
#pragma unroll
  for (int ct = 0; ct < 4; ++ct)
#pragma unroll
    for (int kb = 0; kb < 8; ++kb)
      bf[ct][kb] = *(const h8*)(AhT + (size_t)(cw + ct * 16 + l15) * 256 + kb * 32 + q * 8);

  for (int i = tid; i < 16 * 264; i += 256) ((_Float16*)S[0])[i] = (_Float16)0.f;
  __syncthreads();

  const size_t bbase = (size_t)b * LSEQ;
  float u_cur[4][4], u_nxt[4][4];
  {
    const int t_local = -WARM;
#pragma unroll
    for (int r = 0; r < 4; ++r) {
      int trow = (c0 + q * 4 + r) * CHUNK + t_local;
      const _Float16* p = U + (bbase + (size_t)(trow < 0 ? 0 : trow)) * 256 + cw + l15;
      bool v = trow >= 0;
#pragma unroll
      for (int ct = 0; ct < 4; ++ct) u_cur[ct][r] = v ? (float)p[ct * 16] : 0.f;
    }
  }

  int cb = 0;
  for (int g = 0; g < STEPS; ++g) {
    const int t_local = g - WARM;
    if (g + 1 < STEPS) {  // prefetch next step's U
      const int tn = t_local + 1;
#pragma unroll
      for (int r = 0; r < 4; ++r) {
        int trow = (c0 + q * 4 + r) * CHUNK + tn;
        const _Float16* p = U + (bbase + (size_t)(trow < 0 ? 0 : trow)) * 256 + cw + l15;
        bool v = trow >= 0;
#pragma unroll
        for (int ct = 0; ct < 4; ++ct) u_nxt[ct][r] = v ? (float)p[ct * 16] : 0.f;
      }
    }
    f32x4 acc[4];
#pragma unroll
    for (int ct = 0; ct < 4; ++ct) {
      f32x4 a;
      a[0] = u_cur[ct][0]; a[1] = u_cur[ct][1]; a[2] = u_cur[ct][2]; a[3] = u_cur[ct][3];
      acc[ct] = a;
    }
#pragma unroll
    for (int kb = 0; kb < 8; ++kb) {
      h8 af = *(const h8*)&S[cb][l15][kb * 32 + q * 8];
#pragma unroll
      for (int ct = 0; ct < 4; ++ct)
        acc[ct] = __builtin_amdgcn_mfma_f32_16x16x32_f16(af, bf[ct][kb], acc[ct], 0, 0, 0);
    }
#pragma unroll
    for (int ct = 0; ct < 4; ++ct)
#pragma unroll
      for (int r = 0; r < 4; ++r)
        S[cb ^ 1][q * 4 + r][cw + ct * 16 + l15] = (_Float16)acc[ct][r];
    if (t_local >= 0) {
#pragma unroll
      for (int r = 0; r < 4; ++r) {
        size_t row = bbase + (size_t)((c0 + q * 4 + r) * CHUNK + t_local);
        _Float16* ps = Sh + row * 256 + cw + l15;
#pragma unroll
        for (int ct = 0; ct < 4; ++ct) ps[ct * 16] = (_Float16)acc[ct][r];
      }
    }
    __syncthreads();
    cb ^= 1;
#pragma unroll
    for (int ct = 0; ct < 4; ++ct)
#pragma unroll
      for (int r = 0; r < 4; ++r) u_cur[ct][r] = u_nxt[ct][r];
  }
}

extern "C" void kernel_launch(void* const* d_in, const int* in_sizes, int n_in,
                              void* d_out, int out_size, void* d_ws, size_t ws_size,
                              hipStream_t stream) {
  const float* x = (const float*)d_in[0];
  const float* A = (const float*)d_in[1];
  const float* B = (const float*)d_in[2];
  const float* C = (const float*)d_in[3];

  char* ws = (char*)d_ws;
  _Float16* Sh = (_Float16*)ws;                          // 33.5 MB
  _Float16* AhT = (_Float16*)(ws + 33554432);            // 128 KB
  _Float16* Bh = (_Float16*)(ws + 33554432 + 131072);    // 128 KB
  _Float16* Ch = (_Float16*)(ws + 33554432 + 262144);    // 128 KB
  _Float16* U = (_Float16*)d_out;  // lower 33.5 MB of d_out; dead before gemm_out writes
  float* out = (float*)d_out;

  hipLaunchKernelGGL(k_cvt_mats, dim3(256), dim3(256), 0, stream, A, B, C, AhT, Bh, Ch);
  hipLaunchKernelGGL(k_gemm_u, dim3(1024), dim3(256), 0, stream, x, Bh, U);
  hipLaunchKernelGGL(k_scan, dim3(128), dim3(256), 0, stream, U, AhT, Sh);
  hipLaunchKernelGGL(k_gemm_out, dim3(1024), dim3(256), 0, stream, Sh, Ch, out);
}

// Round 3
// 266.367 us; speedup vs baseline: 1.3835x; 1.3835x over previous
//
#include <hip/hip_runtime.h>

#define BSZ 8
#define LSEQ 8192
#define DDIM 256
#define CHUNK 16
#define WARM 48
#define STEPS (CHUNK + WARM)   // 64
#define CPB 16                 // chains per block
#define UPITCH 528             // ub chain pitch in halves (1024B granule + 32B pad)

typedef float f32x4 __attribute__((ext_vector_type(4)));
typedef _Float16 h8 __attribute__((ext_vector_type(8)));

// per-lane global ptr (base + lane*16B), wave-uniform LDS dest; 16B/lane DMA
__device__ __forceinline__ void gload_lds16(const _Float16* g, _Float16* l) {
  __builtin_amdgcn_global_load_lds(
      (const __attribute__((address_space(1))) unsigned int*)g,
      (__attribute__((address_space(3))) unsigned int*)l, 16, 0, 0);
}

// ---------------- conversions (+ zero page for scan warm-up granules) --------
__global__ void k_cvt_mats(const float* __restrict__ A, const float* __restrict__ B,
                           const float* __restrict__ C, _Float16* __restrict__ AhT,
                           _Float16* __restrict__ Bh, _Float16* __restrict__ Ch,
                           float* __restrict__ Zp) {
  int r = blockIdx.x, c = threadIdx.x;
  AhT[c * 256 + r] = (_Float16)A[r * 256 + c];
  Bh[r * 256 + c] = (_Float16)B[r * 256 + c];
  Ch[r * 256 + c] = (_Float16)C[r * 256 + c];
  if (r == 0) Zp[c] = 0.f;  // 1KB zero page
}

// ---------------- U = x @ B^T ----------------
// 1024 blocks = 256 row-groups x 4 col-groups; sibling col-blocks 64 apart (same XCD).
// B-fragments register-resident (128 VGPR); wave w -> rows [r0+64w, +64), cols [n0,n0+64).
__global__ __launch_bounds__(256, 2) void k_gemm_u(const float* __restrict__ x,
                                                   const _Float16* __restrict__ Bh,
                                                   _Float16* __restrict__ U) {
  const int tid = threadIdx.x, wv = tid >> 6, lane = tid & 63;
  const int l15 = lane & 15, q = lane >> 4;
  const int rblk = (blockIdx.x & 63) + ((blockIdx.x >> 8) << 6);
  const int n0 = ((blockIdx.x >> 6) & 3) * 64;
  const size_t r0 = (size_t)rblk * 256 + wv * 64;
  h8 bf[4][8];
#pragma unroll
  for (int ct = 0; ct < 4; ++ct)
#pragma unroll
    for (int kb = 0; kb < 8; ++kb)
      bf[ct][kb] = *(const h8*)(Bh + (size_t)(n0 + ct * 16 + l15) * 256 + kb * 32 + q * 8);
#pragma unroll
  for (int rt = 0; rt < 4; ++rt) {
    const size_t rr = r0 + rt * 16;
    f32x4 acc[4] = {};
#pragma unroll
    for (int kb = 0; kb < 8; ++kb) {
      const float* xp = x + (rr + l15) * 256 + kb * 32 + q * 8;
      float4 x0 = *(const float4*)xp;
      float4 x1 = *(const float4*)(xp + 4);
      h8 af;
      af[0] = (_Float16)x0.x; af[1] = (_Float16)x0.y; af[2] = (_Float16)x0.z; af[3] = (_Float16)x0.w;
      af[4] = (_Float16)x1.x; af[5] = (_Float16)x1.y; af[6] = (_Float16)x1.z; af[7] = (_Float16)x1.w;
#pragma unroll
      for (int ct = 0; ct < 4; ++ct)
        acc[ct] = __builtin_amdgcn_mfma_f32_16x16x32_f16(af, bf[ct][kb], acc[ct], 0, 0, 0);
    }
#pragma unroll
    for (int ct = 0; ct < 4; ++ct)
#pragma unroll
      for (int r = 0; r < 4; ++r)
        U[(rr + q * 4 + r) * 256 + n0 + ct * 16 + l15] = (_Float16)acc[ct][r];
  }
}

// ---------------- out = S @ C^T ----------------
__global__ __launch_bounds__(256, 2) void k_gemm_out(const _Float16* __restrict__ S,
                                                     const _Float16* __restrict__ Ch,
                                                     float* __restrict__ O) {
  const int tid = threadIdx.x, wv = tid >> 6, lane = tid & 63;
  const int l15 = lane & 15, q = lane >> 4;
  const int rblk = (blockIdx.x & 63) + ((blockIdx.x >> 8) << 6);
  const int n0 = ((blockIdx.x >> 6) & 3) * 64;
  const size_t r0 = (size_t)rblk * 256 + wv * 64;
  h8 bf[4][8];
#pragma unroll
  for (int ct = 0; ct < 4; ++ct)
#pragma unroll
    for (int kb = 0; kb < 8; ++kb)
      bf[ct][kb] = *(const h8*)(Ch + (size_t)(n0 + ct * 16 + l15) * 256 + kb * 32 + q * 8);
#pragma unroll
  for (int rt = 0; rt < 4; ++rt) {
    const size_t rr = r0 + rt * 16;
    f32x4 acc[4] = {};
#pragma unroll
    for (int kb = 0; kb < 8; ++kb) {
      h8 af = *(const h8*)(S + (rr + l15) * 256 + kb * 32 + q * 8);
#pragma unroll
      for (int ct = 0; ct < 4; ++ct)
        acc[ct] = __builtin_amdgcn_mfma_f32_16x16x32_f16(af, bf[ct][kb], acc[ct], 0, 0, 0);
    }
#pragma unroll
    for (int ct = 0; ct < 4; ++ct)
#pragma unroll
      for (int r = 0; r < 4; ++r)
        O[(rr + q * 4 + r) * 256 + n0 + ct * 16 + l15] = acc[ct][r];
  }
}

// ---------------- MFMA scan ----------------
// 4096 chains (8 x 512 chunks of 16), 16 chains/block -> 256 blocks (1/CU).
// U staged 2 steps ahead via global_load_lds (1KB granules, dbuf); warm granules read a
// zero page (granule never mixes warm/valid: chunk*16 and t0 both even). S flushed from
// the state dbuf as coalesced 512B dwordx4 stores one step late.
__global__ __launch_bounds__(256, 1) void k_scan(const _Float16* __restrict__ U,
                                                 const _Float16* __restrict__ AhT,
                                                 const _Float16* __restrict__ Zp,
                                                 _Float16* __restrict__ Sh) {
  __shared__ __align__(16) _Float16 st[2][CPB][264];       // pad 264: 16B-aligned rows, 2-way banks
  __shared__ __align__(16) _Float16 ub[2][CPB * UPITCH];   // 2 slots x 16 chains x (1024B + pad)
  const int tid = threadIdx.x, wv = tid >> 6, lane = tid & 63;
  const int l15 = lane & 15, q = lane >> 4;
  const int cw = wv * 64;
  const int b = blockIdx.x >> 5;
  const int c0 = (blockIdx.x & 31) * CPB;
  const size_t bbase = (size_t)b * LSEQ;

  h8 bf[4][8];
#pragma unroll
  for (int ct = 0; ct < 4; ++ct)
#pragma unroll
    for (int kb = 0; kb < 8; ++kb)
      bf[ct][kb] = *(const h8*)(AhT + (size_t)(cw + ct * 16 + l15) * 256 + kb * 32 + q * 8);

  for (int i = tid; i < CPB * 264; i += 256) ((_Float16*)st[0])[i] = (_Float16)0.f;

  // granule k covers local t = -WARM+2k, +1 for all 16 chains; wave stages chains 4w..4w+3
  auto issue_gran = [&](int k) {
#pragma unroll
    for (int i = 0; i < 4; ++i) {
      const int chain = 4 * wv + i;
      const long row = (long)(c0 + chain) * CHUNK + (-WARM + 2 * k);
      const _Float16* g = (row < 0) ? Zp : (U + (bbase + row) * 256);
      gload_lds16(g + lane * 8, &ub[k & 1][chain * UPITCH]);
    }
  };
  issue_gran(0);
  __syncthreads();  // drains DMA + zero-init

  int cb = 0;
  const int fchain = 4 * wv + q;            // flush: lane covers 32B of chain fchain
  const int foff = l15 * 16;                // halves
  for (int g = 0; g <= STEPS; ++g) {
    const int t = g - WARM;  // this iter computes S_t (g<STEPS); flushes S_{t-1}
    if (g < STEPS && (g & 1) == 0) {
      const int kn = (g >> 1) + 1;
      if (kn < STEPS / 2) issue_gran(kn);
    }
    if (t - 1 >= 0) {  // flush S_{t-1} from st[cb]: 512B coalesced per chain
      const _Float16* srow = &st[cb][fchain][0];
      uint4 w0 = *(const uint4*)(srow + foff);
      uint4 w1 = *(const uint4*)(srow + foff + 8);
      _Float16* dst = Sh + (bbase + (size_t)(c0 + fchain) * CHUNK + (t - 1)) * 256 + foff;
      *(uint4*)dst = w0;
      *(uint4*)(dst + 8) = w1;
    }
    if (g < STEPS) {
      const _Float16* ua = &ub[(g >> 1) & 1][(g & 1) * 256 + cw + l15];
      f32x4 acc[4];
#pragma unroll
      for (int ct = 0; ct < 4; ++ct) {
#pragma unroll
        for (int r = 0; r < 4; ++r)
          acc[ct][r] = (float)ua[(q * 4 + r) * UPITCH + ct * 16];
      }
#pragma unroll
      for (int kb = 0; kb < 8; ++kb) {
        h8 af = *(const h8*)&st[cb][l15][kb * 32 + q * 8];
#pragma unroll
        for (int ct = 0; ct < 4; ++ct)
          acc[ct] = __builtin_amdgcn_mfma_f32_16x16x32_f16(af, bf[ct][kb], acc[ct], 0, 0, 0);
      }
#pragma unroll
      for (int ct = 0; ct < 4; ++ct)
#pragma unroll
        for (int r = 0; r < 4; ++r)
          st[cb ^ 1][q * 4 + r][cw + ct * 16 + l15] = (_Float16)acc[ct][r];
    }
    __syncthreads();
    cb ^= 1;
  }
}

extern "C" void kernel_launch(void* const* d_in, const int* in_sizes, int n_in,
                              void* d_out, int out_size, void* d_ws, size_t ws_size,
                              hipStream_t stream) {
  const float* x = (const float*)d_in[0];
  const float* A = (const float*)d_in[1];
  const float* B = (const float*)d_in[2];
  const float* C = (const float*)d_in[3];

  char* ws = (char*)d_ws;
  _Float16* Sh = (_Float16*)ws;                           // 33.5 MB
  _Float16* AhT = (_Float16*)(ws + 33554432);             // 128 KB
  _Float16* Bh = (_Float16*)(ws + 33554432 + 131072);     // 128 KB
  _Float16* Ch = (_Float16*)(ws + 33554432 + 262144);     // 128 KB
  float* Zp = (float*)(ws + 33554432 + 393216);           // 1 KB zeros
  _Float16* U = (_Float16*)d_out;  // first 33.5 MB of d_out; dead before gemm_out writes
  float* out = (float*)d_out;

  hipLaunchKernelGGL(k_cvt_mats, dim3(256), dim3(256), 0, stream, A, B, C, AhT, Bh, Ch, Zp);
  hipLaunchKernelGGL(k_gemm_u, dim3(1024), dim3(256), 0, stream, x, Bh, U);
  hipLaunchKernelGGL(k_scan, dim3(256), dim3(256), 0, stream, U, AhT, (const _Float16*)Zp, Sh);
  hipLaunchKernelGGL(k_gemm_out, dim3(1024), dim3(256), 0, stream, Sh, Ch, out);
}